// Round 15
// baseline (426.215 us; speedup 1.0000x reference)
//
#include <hip/hip_runtime.h>
#include <math.h>
#include <float.h>

#define BATCH 16
#define SEQ 96
#define NNODE 256
#define CFREQ 9
#define MNODE (NNODE * CFREQ)      // 2304
#define BM (BATCH * MNODE)         // 36864
#define KNN 8
#define EMBED 128
#define HIDDEN 64
#define TN (SEQ * NNODE)           // 24576
#define KCAP 256

__constant__ float COS16[16] = {
    1.0f, 0.9238795325112867f, 0.7071067811865476f, 0.3826834323650898f,
    0.0f, -0.3826834323650898f, -0.7071067811865476f, -0.9238795325112867f,
    -1.0f, -0.9238795325112867f, -0.7071067811865476f, -0.3826834323650898f,
    0.0f, 0.3826834323650898f, 0.7071067811865476f, 0.9238795325112867f};
__constant__ float SIN16[16] = {
    0.0f, 0.3826834323650898f, 0.7071067811865476f, 0.9238795325112867f,
    1.0f, 0.9238795325112867f, 0.7071067811865476f, 0.3826834323650898f,
    0.0f, -0.3826834323650898f, -0.7071067811865476f, -0.9238795325112867f,
    -1.0f, -0.9238795325112867f, -0.7071067811865476f, -0.3826834323650898f};

static __device__ __forceinline__ float silu_f(float x) {
    return x / (1.0f + expf(-x));
}

// trend[b,t,n] = (x[t-1]+x[t]+x[t+1])/3 with edge clamp; layout (B,T,N)
__global__ void trend_kernel(const float* __restrict__ x, float* __restrict__ trend) {
    int gid = blockIdx.x * blockDim.x + threadIdx.x;
    if (gid >= BATCH * TN) return;
    int b = gid / TN;
    int rem = gid - b * TN;
    int t = rem / NNODE;
    int n = rem - t * NNODE;
    int tm = t > 0 ? t - 1 : 0;
    int tp = t < SEQ - 1 ? t + 1 : SEQ - 1;
    const float* xb = x + b * TN;
    float v = (xb[tm * NNODE + n] + xb[t * NNODE + n] + xb[tp * NNODE + n]) * (1.0f / 3.0f);
    trend[gid] = v;
}

// S[b, m] = ortho-rfft16 of (x - trend) over first 16 t; m = n*9 + c
__global__ void fft_kernel(const float* __restrict__ x, const float* __restrict__ trend,
                           float* __restrict__ S) {
    int gid = blockIdx.x * blockDim.x + threadIdx.x;
    if (gid >= BM) return;
    int b = gid / MNODE;
    int m = gid - b * MNODE;
    int n = m / CFREQ;
    int c = m - n * CFREQ;
    const float* xb = x + b * TN + n;
    const float* tb = trend + b * TN + n;
    float re = 0.0f, im = 0.0f;
    #pragma unroll
    for (int t = 0; t < 16; ++t) {
        float s = xb[t * NNODE] - tb[t * NNODE];
        int k = (c * t) & 15;
        re += s * COS16[k];
        im -= s * SIN16[k];
    }
    S[gid * 2 + 0] = re * 0.25f;
    S[gid * 2 + 1] = im * 0.25f;
}

// One WAVE per row, 8 rows per 512-thread block (round-6's proven 85%-occupancy
// shape). Exact top-8 via 3-phase filter (round-8's proven structure):
//  P1: 36 lane-candidate distances cached in regs; per-lane min.
//  T : 8 butterfly-min+eliminate rounds over lane minima (T >= true d8).
//  P2: append u64 keys (sortable_d | j) of candidates with d <= T to row LDS buf.
//  P3: exact u64 top-8 + 8-round merge over the small buffer.
//  Overflow (> KCAP, pathological ties only) -> exact u64 scan fallback.
// LDS: f 18.4 KB + kbuf 16.4 KB -> 34.8 KB => 4 blocks/CU x 8 waves = 32 waves/CU.
__global__ void __launch_bounds__(512) knn_kernel(const float* __restrict__ S,
                                                  int* __restrict__ idx, int* __restrict__ cnt) {
    __shared__ float2 f[MNODE];                        // 18432 B
    __shared__ unsigned long long kbuf[8][KCAP];       // 16384 B
    __shared__ int bcnt[8];
    int b = blockIdx.y;
    int tid = threadIdx.x;
    for (int t = tid; t < MNODE; t += 512) {
        f[t] = make_float2(S[(b * MNODE + t) * 2 + 0], S[(b * MNODE + t) * 2 + 1]);
    }
    if (tid < 8) bcnt[tid] = 0;
    __syncthreads();
    int wave = tid >> 6, lane = tid & 63;
    int i = blockIdx.x * 8 + wave;
    float2 fi = f[i];
    float xi0 = fi.x, yi0 = fi.y;
    float sqi = __fadd_rn(__fmul_rn(xi0, xi0), __fmul_rn(yi0, yi0));

    // Phase 1: distances cached, per-lane min
    float d[36];
    float mymin = FLT_MAX;
    #pragma unroll
    for (int k = 0; k < 36; ++k) {
        int j = lane + (k << 6);
        float2 fj = f[j];
        float sqj = __fadd_rn(__fmul_rn(fj.x, fj.x), __fmul_rn(fj.y, fj.y));
        float dot = __fadd_rn(__fmul_rn(xi0, fj.x), __fmul_rn(yi0, fj.y));
        float dd = __fsub_rn(__fadd_rn(sqi, sqj), __fmul_rn(2.0f, dot));
        if (j == i) dd = FLT_MAX;
        d[k] = dd;
        mymin = fminf(mymin, dd);
    }
    // Threshold: 8 rounds of global-min + eliminate
    float v = mymin, T = FLT_MAX;
    #pragma unroll
    for (int r = 0; r < KNN; ++r) {
        float g = v;
        #pragma unroll
        for (int off = 32; off > 0; off >>= 1) g = fminf(g, __shfl_xor(g, off, 64));
        T = g;
        if (v == g) v = FLT_MAX;
    }
    // Phase 2: append survivors' exact keys
    unsigned long long* mybuf = kbuf[wave];
    #pragma unroll
    for (int k = 0; k < 36; ++k) {
        if (d[k] <= T) {
            int j = lane + (k << 6);
            unsigned int bits = __float_as_uint(d[k]);
            if (bits == 0x80000000u) bits = 0u;
            unsigned int s = bits ^ (unsigned int)(((int)bits >> 31) | 0x80000000);
            unsigned long long key = ((unsigned long long)s << 32) | (unsigned int)j;
            int p = atomicAdd(&bcnt[wave], 1);
            if (p < KCAP) mybuf[p] = key;
        }
    }
    __syncthreads();   // make appends visible (block-uniform point)

    const unsigned long long SENT = ~0ull;
    unsigned long long k0 = SENT, k1 = SENT, k2 = SENT, k3 = SENT,
                       k4 = SENT, k5 = SENT, k6 = SENT, k7 = SENT;
    auto insert = [&](unsigned long long key) {
        if (key < k7) {
            k7 = key;
            if (k7 < k6) { unsigned long long t = k6; k6 = k7; k7 = t; }
            if (k6 < k5) { unsigned long long t = k5; k5 = k6; k6 = t; }
            if (k5 < k4) { unsigned long long t = k4; k4 = k5; k5 = t; }
            if (k4 < k3) { unsigned long long t = k3; k3 = k4; k4 = t; }
            if (k3 < k2) { unsigned long long t = k2; k2 = k3; k3 = t; }
            if (k2 < k1) { unsigned long long t = k1; k1 = k2; k2 = t; }
            if (k1 < k0) { unsigned long long t = k0; k0 = k1; k1 = t; }
        }
    };
    int total = bcnt[wave];
    if (total > KCAP) {
        // pathological ties: exact scan over cached distances
        #pragma unroll
        for (int k = 0; k < 36; ++k) {
            int j = lane + (k << 6);
            unsigned int bits = __float_as_uint(d[k]);
            if (bits == 0x80000000u) bits = 0u;
            unsigned int s = bits ^ (unsigned int)(((int)bits >> 31) | 0x80000000);
            insert(((unsigned long long)s << 32) | (unsigned int)j);
        }
    } else {
        for (int p = lane; p < total; p += 64) insert(mybuf[p]);
    }
    // 8-round wave merge: lane r keeps winner r
    unsigned long long mywin = 0;
    #pragma unroll
    for (int r = 0; r < KNN; ++r) {
        unsigned long long h = k0;
        #pragma unroll
        for (int off = 32; off > 0; off >>= 1) {
            unsigned long long o = __shfl_xor(h, off, 64);
            if (o < h) h = o;
        }
        if (lane == r) mywin = h;
        if (k0 == h) {
            k0 = k1; k1 = k2; k2 = k3; k3 = k4; k4 = k5; k5 = k6; k6 = k7; k7 = SENT;
        }
    }
    if (lane < KNN) {
        int j = (int)(unsigned int)(mywin & 0xFFFFFFFFull);
        idx[(b * MNODE + i) * KNN + lane] = j;
        atomicAdd(&cnt[b * MNODE + j], 1);
    }
}

__global__ void dinv_kernel(const int* __restrict__ cnt, float* __restrict__ dinv) {
    int gid = blockIdx.x * blockDim.x + threadIdx.x;
    if (gid >= BM) return;
    float deg = (float)(KNN + cnt[gid]);
    dinv[gid] = 1.0f / sqrtf(deg + 1e-8f);
}

// exclusive prefix sum over cnt[BM] -> offs[BM]; single block of 256 threads
__global__ void __launch_bounds__(256) scan_kernel(const int* __restrict__ cnt,
                                                   int* __restrict__ offs) {
    __shared__ int part[256];
    int tid = threadIdx.x;
    const int per = BM / 256;   // 144
    int base = tid * per;
    int s = 0;
    for (int k = 0; k < per; ++k) s += cnt[base + k];
    part[tid] = s;
    __syncthreads();
    if (tid == 0) {
        int run = 0;
        for (int t = 0; t < 256; ++t) { int tmp = part[t]; part[t] = run; run += tmp; }
    }
    __syncthreads();
    int run = part[tid];
    for (int k = 0; k < per; ++k) { offs[base + k] = run; run += cnt[base + k]; }
}

// scatter each directed edge i->j into j's reverse list (int atomics for slots)
__global__ void fill_kernel(const int* __restrict__ idx, const int* __restrict__ offs,
                            int* __restrict__ fptr, int* __restrict__ rev) {
    int gid = blockIdx.x * blockDim.x + threadIdx.x;
    if (gid >= BM * KNN) return;
    int b = gid / (MNODE * KNN);
    int rem = gid - b * (MNODE * KNN);
    int i = rem / KNN;
    int gj = b * MNODE + idx[gid];
    int pos = atomicAdd(&fptr[gj], 1);
    rev[offs[gj] + pos] = b * MNODE + i;
}

// zA[i][c] = sum over neighbors j (both directions) with j%9==c of w_ij * S[j]
__global__ void __launch_bounds__(256) gather1_kernel(
    const int* __restrict__ idx, const int* __restrict__ offs, const int* __restrict__ cnt,
    const int* __restrict__ rev, const float* __restrict__ dinv, const float* __restrict__ S,
    float* __restrict__ zA) {
    int gi = blockIdx.x * blockDim.x + threadIdx.x;
    if (gi >= BM) return;
    int b = gi / MNODE;
    float acc[2 * CFREQ];
    #pragma unroll
    for (int k = 0; k < 2 * CFREQ; ++k) acc[k] = 0.0f;
    float di = dinv[gi] * 0.5f;   // fold ew/S_SCALE
    #pragma unroll
    for (int k = 0; k < KNN; ++k) {
        int gj = b * MNODE + idx[gi * KNN + k];
        float w = di * dinv[gj];
        int c = gj % CFREQ;
        acc[2 * c + 0] += w * S[gj * 2 + 0];
        acc[2 * c + 1] += w * S[gj * 2 + 1];
    }
    int o = offs[gi], e = o + cnt[gi];
    for (int p = o; p < e; ++p) {
        int gk = rev[p];
        float w = di * dinv[gk];
        int c = gk % CFREQ;
        acc[2 * c + 0] += w * S[gk * 2 + 0];
        acc[2 * c + 1] += w * S[gk * 2 + 1];
    }
    #pragma unroll
    for (int k = 0; k < 2 * CFREQ; ++k) zA[gi * 2 * CFREQ + k] = acc[k];
}

// zB[i][c] = sum over neighbors j (both directions) of w_ij * zA[j][c]
__global__ void __launch_bounds__(256) gather2_kernel(
    const int* __restrict__ idx, const int* __restrict__ offs, const int* __restrict__ cnt,
    const int* __restrict__ rev, const float* __restrict__ dinv, const float* __restrict__ zA,
    float* __restrict__ zB) {
    int gi = blockIdx.x * blockDim.x + threadIdx.x;
    if (gi >= BM) return;
    int b = gi / MNODE;
    float acc[2 * CFREQ];
    #pragma unroll
    for (int k = 0; k < 2 * CFREQ; ++k) acc[k] = 0.0f;
    float di = dinv[gi] * 0.5f;
    #pragma unroll
    for (int k = 0; k < KNN; ++k) {
        int gj = b * MNODE + idx[gi * KNN + k];
        float w = di * dinv[gj];
        const float* za = zA + gj * 2 * CFREQ;
        #pragma unroll
        for (int c = 0; c < CFREQ; ++c) {
            float2 v = ((const float2*)za)[c];
            acc[2 * c + 0] += w * v.x;
            acc[2 * c + 1] += w * v.y;
        }
    }
    int o = offs[gi], e = o + cnt[gi];
    for (int p = o; p < e; ++p) {
        int gk = rev[p];
        float w = di * dinv[gk];
        const float* za = zA + gk * 2 * CFREQ;
        #pragma unroll
        for (int c = 0; c < CFREQ; ++c) {
            float2 v = ((const float2*)za)[c];
            acc[2 * c + 0] += w * v.x;
            acc[2 * c + 1] += w * v.y;
        }
    }
    #pragma unroll
    for (int k = 0; k < 2 * CFREQ; ++k) zB[gi * 2 * CFREQ + k] = acc[k];
}

// FE[c,e] = freq_emb[c,:] @ (Wr + i Wi)^T  (9 x 128 complex)
__global__ void fe_kernel(const float* __restrict__ femb, const float* __restrict__ Wr,
                          const float* __restrict__ Wi, float* __restrict__ FE) {
    int gid = blockIdx.x * blockDim.x + threadIdx.x;
    if (gid >= CFREQ * EMBED) return;
    int c = gid / EMBED;
    int e = gid - c * EMBED;
    float ar = 0.0f, ai = 0.0f;
    for (int k = 0; k < EMBED; ++k) {
        float f = femb[c * EMBED + k];
        ar += f * Wr[e * EMBED + k];
        ai += f * Wi[e * EMBED + k];
    }
    FE[gid * 2 + 0] = ar;
    FE[gid * 2 + 1] = ai;
}

// per row r: z_acc (9 complex) -> u = z_acc . FE -> csilu -> eo projection (complex scalar)
__global__ void __launch_bounds__(256) rowproj_kernel(
    const float* __restrict__ S, const float* __restrict__ zA, const float* __restrict__ zB,
    const float* __restrict__ FE, const float* __restrict__ eoWr, const float* __restrict__ eoWi,
    const float* __restrict__ theta, const float* __restrict__ approx,
    float* __restrict__ Sout) {
    int wave = threadIdx.x >> 6;
    int lane = threadIdx.x & 63;
    int r = blockIdx.x * 4 + wave;
    if (r >= BM) return;
    float a0 = theta[0] * approx[0] + theta[1] * approx[3];
    float a1 = theta[0] * approx[1] + theta[1] * approx[4];
    float a2 = theta[0] * approx[2] + theta[1] * approx[5];
    float ca = a0 - a2, cb = -a1, cc = 2.0f * a2;
    int cr = r % CFREQ;
    float sr = S[r * 2 + 0], si = S[r * 2 + 1];
    int e1 = lane + 64;
    float ur0 = 0.0f, ui0 = 0.0f, ur1 = 0.0f, ui1 = 0.0f;
    #pragma unroll
    for (int c = 0; c < CFREQ; ++c) {
        float zr = cb * zA[(r * CFREQ + c) * 2 + 0] + cc * zB[(r * CFREQ + c) * 2 + 0];
        float zi = cb * zA[(r * CFREQ + c) * 2 + 1] + cc * zB[(r * CFREQ + c) * 2 + 1];
        if (c == cr) { zr += ca * sr; zi += ca * si; }
        float fr0 = FE[(c * EMBED + lane) * 2 + 0], fi0 = FE[(c * EMBED + lane) * 2 + 1];
        float fr1 = FE[(c * EMBED + e1) * 2 + 0],  fi1 = FE[(c * EMBED + e1) * 2 + 1];
        ur0 += zr * fr0 - zi * fi0;  ui0 += zr * fi0 + zi * fr0;
        ur1 += zr * fr1 - zi * fi1;  ui1 += zr * fi1 + zi * fr1;
    }
    float hr0 = silu_f(ur0), hi0 = silu_f(ui0);
    float hr1 = silu_f(ur1), hi1 = silu_f(ui1);
    float wr0 = eoWr[lane], wi0 = eoWi[lane], wr1 = eoWr[e1], wi1 = eoWi[e1];
    float p = hr0 * wr0 - hi0 * wi0 + hr1 * wr1 - hi1 * wi1;
    float q = hr0 * wi0 + hi0 * wr0 + hr1 * wi1 + hi1 * wr1;
    #pragma unroll
    for (int off = 32; off > 0; off >>= 1) {
        p += __shfl_down(p, off, 64);
        q += __shfl_down(q, off, 64);
    }
    if (lane == 0) {
        Sout[r * 2 + 0] = p;
        Sout[r * 2 + 1] = q;
    }
}

// per (b,n): irfft96 -> inorm+silu -> W1 -> inorm+silu -> W2 -> + trend_emb -> W3 -> out
__global__ void __launch_bounds__(128) head_kernel(
    const float* __restrict__ Sout, const float* __restrict__ trend,
    const float* __restrict__ n1w, const float* __restrict__ n1b,
    const float* __restrict__ n2w, const float* __restrict__ n2b,
    const float* __restrict__ W1w, const float* __restrict__ W1b,
    const float* __restrict__ W2w, const float* __restrict__ W2b,
    const float* __restrict__ Wtw, const float* __restrict__ Wtb,
    const float* __restrict__ W3w, const float* __restrict__ W3b,
    float* __restrict__ out) {
    __shared__ float tabc[96], tabs[96], hraw[96], sH[96], tbuf[96];
    __shared__ float srow[18], h2[64], s3[64], red[2];
    __shared__ float wbuf[6240];
    int bn = blockIdx.x;
    int b = bn >> 8;
    int n = bn & 255;
    int tid = threadIdx.x;
    if (tid < 96) {
        double a = 6.283185307179586476925286766559 * (double)tid / 96.0;
        tabc[tid] = (float)cos(a);
        tabs[tid] = (float)sin(a);
        tbuf[tid] = trend[b * TN + tid * NNODE + n];
    }
    if (tid < 18) srow[tid] = Sout[bn * 18 + tid];
    __syncthreads();
    float hv = 0.0f;
    if (tid < 96) {
        float acc = srow[0];   // Im(bin0) ignored by irfft
        #pragma unroll
        for (int c = 1; c < CFREQ; ++c) {
            int k = (c * tid) % 96;
            acc += 2.0f * (srow[2 * c] * tabc[k] - srow[2 * c + 1] * tabs[k]);
        }
        hv = acc * 0.10206207261596575f;  // 1/sqrt(96)
        hraw[tid] = hv;
    }
    __syncthreads();
    if (tid < 64) {
        float v = hraw[tid] + ((tid < 32) ? hraw[64 + tid] : 0.0f);
        #pragma unroll
        for (int off = 32; off > 0; off >>= 1) v += __shfl_down(v, off, 64);
        if (tid == 0) red[0] = v * (1.0f / 96.0f);
    }
    __syncthreads();
    float mu = red[0];
    if (tid < 64) {
        float d0 = hraw[tid] - mu;
        float v = d0 * d0;
        if (tid < 32) { float d1 = hraw[64 + tid] - mu; v += d1 * d1; }
        #pragma unroll
        for (int off = 32; off > 0; off >>= 1) v += __shfl_down(v, off, 64);
        if (tid == 0) red[1] = v * (1.0f / 96.0f);
    }
    __syncthreads();
    float var = red[1];
    if (tid < 96) {
        float xn = (hv - mu) / sqrtf(var + 1e-5f) * n1w[n] + n1b[n];
        sH[tid] = silu_f(xn);
    }
    for (int i = tid; i < HIDDEN * 96; i += 128) {
        int rr = i / 96;
        wbuf[rr * 97 + (i - rr * 96)] = W1w[i];
    }
    __syncthreads();
    float v1 = 0.0f;
    if (tid < 64) {
        float acc = W1b[tid];
        #pragma unroll 8
        for (int t = 0; t < 96; ++t) acc += sH[t] * wbuf[tid * 97 + t];
        v1 = acc;
    }
    if (tid < 64) {
        float s = v1;
        #pragma unroll
        for (int off = 32; off > 0; off >>= 1) s += __shfl_down(s, off, 64);
        s = __shfl(s, 0, 64);
        float mu2 = s * (1.0f / 64.0f);
        float d = v1 - mu2;
        float vs = d * d;
        #pragma unroll
        for (int off = 32; off > 0; off >>= 1) vs += __shfl_down(vs, off, 64);
        vs = __shfl(vs, 0, 64);
        float var2 = vs * (1.0f / 64.0f);
        float xn = (v1 - mu2) / sqrtf(var2 + 1e-5f) * n2w[n] + n2b[n];
        h2[tid] = silu_f(xn);
    }
    __syncthreads();   // wbuf(W1) reads + h2 writes done
    for (int i = tid; i < HIDDEN * HIDDEN; i += 128) {
        wbuf[(i >> 6) * 65 + (i & 63)] = W2w[i];
    }
    __syncthreads();
    float v3 = 0.0f;
    if (tid < 64) {
        float acc = W2b[tid];
        #pragma unroll 8
        for (int h = 0; h < 64; ++h) acc += h2[h] * wbuf[tid * 65 + h];
        v3 = acc;
    }
    __syncthreads();   // wbuf(W2) reads done
    for (int i = tid; i < HIDDEN * 96; i += 128) {
        int rr = i / 96;
        wbuf[rr * 97 + (i - rr * 96)] = Wtw[i];
    }
    __syncthreads();
    if (tid < 64) {
        float acc = Wtb[tid];
        #pragma unroll 8
        for (int t = 0; t < 96; ++t) acc += tbuf[t] * wbuf[tid * 97 + t];
        s3[tid] = v3 + acc;
    }
    __syncthreads();   // wbuf(Wt) reads + s3 writes done
    for (int i = tid; i < 96 * HIDDEN; i += 128) {
        wbuf[(i >> 6) * 65 + (i & 63)] = W3w[i];
    }
    __syncthreads();
    if (tid < 96) {
        float acc = W3b[tid];
        #pragma unroll 8
        for (int h = 0; h < 64; ++h) acc += s3[h] * wbuf[tid * 65 + h];
        out[bn * 96 + tid] = acc;
    }
}

extern "C" void kernel_launch(void* const* d_in, const int* in_sizes, int n_in,
                              void* d_out, int out_size, void* d_ws, size_t ws_size,
                              hipStream_t stream) {
    const float* x     = (const float*)d_in[0];
    const float* approx= (const float*)d_in[1];
    const float* theta = (const float*)d_in[2];
    const float* frWr  = (const float*)d_in[3];
    const float* frWi  = (const float*)d_in[4];
    const float* eoWr  = (const float*)d_in[5];
    const float* eoWi  = (const float*)d_in[6];
    const float* femb  = (const float*)d_in[7];
    const float* n1w   = (const float*)d_in[8];
    const float* n1b   = (const float*)d_in[9];
    const float* n2w   = (const float*)d_in[10];
    const float* n2b   = (const float*)d_in[11];
    const float* W1w   = (const float*)d_in[12];
    const float* W1b   = (const float*)d_in[13];
    const float* W2w   = (const float*)d_in[14];
    const float* W2b   = (const float*)d_in[15];
    const float* Wtw   = (const float*)d_in[16];
    const float* Wtb   = (const float*)d_in[17];
    const float* W3w   = (const float*)d_in[18];
    const float* W3b   = (const float*)d_in[19];
    float* out = (float*)d_out;

    char* ws = (char*)d_ws;
    size_t off = 0;
    auto alloc = [&](size_t bytes) -> void* {
        void* p = ws + off;
        off = (off + bytes + 255) & ~(size_t)255;
        return p;
    };
    float* trend = (float*)alloc((size_t)BATCH * TN * 4);
    float* S     = (float*)alloc((size_t)BM * 2 * 4);
    int*   idx   = (int*)  alloc((size_t)BM * KNN * 4);
    float* dinv  = (float*)alloc((size_t)BM * 4);
    float* FE    = (float*)alloc((size_t)CFREQ * EMBED * 2 * 4);
    float* Sout  = (float*)alloc((size_t)BM * 2 * 4);
    int*   offs  = (int*)  alloc((size_t)BM * 4);
    int*   rev   = (int*)  alloc((size_t)BM * KNN * 4);
    float* zA    = (float*)alloc((size_t)BM * CFREQ * 2 * 4);
    float* zB    = (float*)alloc((size_t)BM * CFREQ * 2 * 4);
    char*  zbase = ws + off;
    int*   cnt   = (int*)  alloc((size_t)BM * 4);
    int*   fptr  = (int*)  alloc((size_t)BM * 4);
    size_t zbytes = (size_t)(ws + off - zbase);

    hipMemsetAsync(zbase, 0, zbytes, stream);   // cnt + fptr only (288 KB)

    trend_kernel<<<(BATCH * TN + 255) / 256, 256, 0, stream>>>(x, trend);
    fft_kernel<<<(BM + 255) / 256, 256, 0, stream>>>(x, trend, S);
    knn_kernel<<<dim3(MNODE / 8, BATCH), 512, 0, stream>>>(S, idx, cnt);
    dinv_kernel<<<(BM + 255) / 256, 256, 0, stream>>>(cnt, dinv);
    scan_kernel<<<1, 256, 0, stream>>>(cnt, offs);
    fill_kernel<<<(BM * KNN + 255) / 256, 256, 0, stream>>>(idx, offs, fptr, rev);
    gather1_kernel<<<(BM + 255) / 256, 256, 0, stream>>>(idx, offs, cnt, rev, dinv, S, zA);
    gather2_kernel<<<(BM + 255) / 256, 256, 0, stream>>>(idx, offs, cnt, rev, dinv, zA, zB);
    fe_kernel<<<(CFREQ * EMBED + 255) / 256, 256, 0, stream>>>(femb, frWr, frWi, FE);
    rowproj_kernel<<<BM / 4, 256, 0, stream>>>(S, zA, zB, FE, eoWr, eoWi, theta, approx, Sout);
    head_kernel<<<BATCH * NNODE, 128, 0, stream>>>(Sout, trend, n1w, n1b, n2w, n2b,
                                                   W1w, W1b, W2w, W2b, Wtw, Wtb, W3w, W3b, out);
}

// Round 17
// 376.307 us; speedup vs baseline: 1.1326x; 1.1326x over previous
//
#include <hip/hip_runtime.h>
#include <math.h>
#include <float.h>

#define BATCH 16
#define SEQ 96
#define NNODE 256
#define CFREQ 9
#define MNODE (NNODE * CFREQ)      // 2304
#define BM (BATCH * MNODE)         // 36864
#define KNN 8
#define EMBED 128
#define HIDDEN 64
#define TN (SEQ * NNODE)           // 24576
#define KCAP 256

__constant__ float COS16[16] = {
    1.0f, 0.9238795325112867f, 0.7071067811865476f, 0.3826834323650898f,
    0.0f, -0.3826834323650898f, -0.7071067811865476f, -0.9238795325112867f,
    -1.0f, -0.9238795325112867f, -0.7071067811865476f, -0.3826834323650898f,
    0.0f, 0.3826834323650898f, 0.7071067811865476f, 0.9238795325112867f};
__constant__ float SIN16[16] = {
    0.0f, 0.3826834323650898f, 0.7071067811865476f, 0.9238795325112867f,
    1.0f, 0.9238795325112867f, 0.7071067811865476f, 0.3826834323650898f,
    0.0f, -0.3826834323650898f, -0.7071067811865476f, -0.9238795325112867f,
    -1.0f, -0.9238795325112867f, -0.7071067811865476f, -0.3826834323650898f};

static __device__ __forceinline__ float silu_f(float x) {
    return x / (1.0f + expf(-x));
}

// trend[b,t,n] = (x[t-1]+x[t]+x[t+1])/3 with edge clamp; layout (B,T,N)
__global__ void trend_kernel(const float* __restrict__ x, float* __restrict__ trend) {
    int gid = blockIdx.x * blockDim.x + threadIdx.x;
    if (gid >= BATCH * TN) return;
    int b = gid / TN;
    int rem = gid - b * TN;
    int t = rem / NNODE;
    int n = rem - t * NNODE;
    int tm = t > 0 ? t - 1 : 0;
    int tp = t < SEQ - 1 ? t + 1 : SEQ - 1;
    const float* xb = x + b * TN;
    float v = (xb[tm * NNODE + n] + xb[t * NNODE + n] + xb[tp * NNODE + n]) * (1.0f / 3.0f);
    trend[gid] = v;
}

// S[b, m] = ortho-rfft16 of (x - trend) over first 16 t; m = n*9 + c
__global__ void fft_kernel(const float* __restrict__ x, const float* __restrict__ trend,
                           float* __restrict__ S) {
    int gid = blockIdx.x * blockDim.x + threadIdx.x;
    if (gid >= BM) return;
    int b = gid / MNODE;
    int m = gid - b * MNODE;
    int n = m / CFREQ;
    int c = m - n * CFREQ;
    const float* xb = x + b * TN + n;
    const float* tb = trend + b * TN + n;
    float re = 0.0f, im = 0.0f;
    #pragma unroll
    for (int t = 0; t < 16; ++t) {
        float s = xb[t * NNODE] - tb[t * NNODE];
        int k = (c * t) & 15;
        re += s * COS16[k];
        im -= s * SIN16[k];
    }
    S[gid * 2 + 0] = re * 0.25f;
    S[gid * 2 + 1] = im * 0.25f;
}

// One WAVE per row, 4 rows per 256-block. Exact top-8 via 3-phase filter
// (round-14's PASSING structure; only change: __launch_bounds__(256, 8) to cap
// VGPRs at 64 — round-15 showed the 68-VGPR allocation halves wave capacity):
//  P1: 36 lane-candidate distances cached in regs; per-lane min.
//  T : 8 butterfly-min+eliminate rounds over lane minima (T >= true d8).
//  P2: append u64 keys (sortable_d | j) of candidates with d <= T to row LDS buf.
//  P3: exact u64 top-8 + 8-round merge over the small buffer.
//  Overflow (> KCAP, pathological ties only) -> exact scan over cached d.
__global__ void __launch_bounds__(256, 8) knn_kernel(const float* __restrict__ S,
                                                     int* __restrict__ idx, int* __restrict__ cnt) {
    __shared__ float2 f[MNODE];                        // 18432 B
    __shared__ unsigned long long kbuf[4][KCAP];       // 8192 B
    __shared__ int bcnt[4];
    int b = blockIdx.y;
    int tid = threadIdx.x;
    for (int t = tid; t < MNODE; t += 256) {
        f[t] = make_float2(S[(b * MNODE + t) * 2 + 0], S[(b * MNODE + t) * 2 + 1]);
    }
    if (tid < 4) bcnt[tid] = 0;
    __syncthreads();
    int wave = tid >> 6, lane = tid & 63;
    int i = blockIdx.x * 4 + wave;
    float2 fi = f[i];
    float xi0 = fi.x, yi0 = fi.y;
    float sqi = __fadd_rn(__fmul_rn(xi0, xi0), __fmul_rn(yi0, yi0));

    // Phase 1: distances cached, per-lane min
    float d[36];
    float mymin = FLT_MAX;
    #pragma unroll
    for (int k = 0; k < 36; ++k) {
        int j = lane + (k << 6);
        float2 fj = f[j];
        float sqj = __fadd_rn(__fmul_rn(fj.x, fj.x), __fmul_rn(fj.y, fj.y));
        float dot = __fadd_rn(__fmul_rn(xi0, fj.x), __fmul_rn(yi0, fj.y));
        float dd = __fsub_rn(__fadd_rn(sqi, sqj), __fmul_rn(2.0f, dot));
        if (j == i) dd = FLT_MAX;
        d[k] = dd;
        mymin = fminf(mymin, dd);
    }
    // Threshold: 8 rounds of global-min + eliminate
    float v = mymin, T = FLT_MAX;
    #pragma unroll
    for (int r = 0; r < KNN; ++r) {
        float g = v;
        #pragma unroll
        for (int off = 32; off > 0; off >>= 1) g = fminf(g, __shfl_xor(g, off, 64));
        T = g;
        if (v == g) v = FLT_MAX;
    }
    // Phase 2: append survivors' exact keys
    unsigned long long* mybuf = kbuf[wave];
    #pragma unroll
    for (int k = 0; k < 36; ++k) {
        if (d[k] <= T) {
            int j = lane + (k << 6);
            unsigned int bits = __float_as_uint(d[k]);
            if (bits == 0x80000000u) bits = 0u;
            unsigned int s = bits ^ (unsigned int)(((int)bits >> 31) | 0x80000000);
            unsigned long long key = ((unsigned long long)s << 32) | (unsigned int)j;
            int p = atomicAdd(&bcnt[wave], 1);
            if (p < KCAP) mybuf[p] = key;
        }
    }
    __syncthreads();   // make appends visible (block-uniform point)

    const unsigned long long SENT = ~0ull;
    unsigned long long k0 = SENT, k1 = SENT, k2 = SENT, k3 = SENT,
                       k4 = SENT, k5 = SENT, k6 = SENT, k7 = SENT;
    auto insert = [&](unsigned long long key) {
        if (key < k7) {
            k7 = key;
            if (k7 < k6) { unsigned long long t = k6; k6 = k7; k7 = t; }
            if (k6 < k5) { unsigned long long t = k5; k5 = k6; k6 = t; }
            if (k5 < k4) { unsigned long long t = k4; k4 = k5; k5 = t; }
            if (k4 < k3) { unsigned long long t = k3; k3 = k4; k4 = t; }
            if (k3 < k2) { unsigned long long t = k2; k2 = k3; k3 = t; }
            if (k2 < k1) { unsigned long long t = k1; k1 = k2; k2 = t; }
            if (k1 < k0) { unsigned long long t = k0; k0 = k1; k1 = t; }
        }
    };
    int total = bcnt[wave];
    if (total > KCAP) {
        // pathological ties: exact scan over cached distances
        #pragma unroll
        for (int k = 0; k < 36; ++k) {
            int j = lane + (k << 6);
            unsigned int bits = __float_as_uint(d[k]);
            if (bits == 0x80000000u) bits = 0u;
            unsigned int s = bits ^ (unsigned int)(((int)bits >> 31) | 0x80000000);
            insert(((unsigned long long)s << 32) | (unsigned int)j);
        }
    } else {
        for (int p = lane; p < total; p += 64) insert(mybuf[p]);
    }
    // 8-round wave merge: lane r keeps winner r
    unsigned long long mywin = 0;
    #pragma unroll
    for (int r = 0; r < KNN; ++r) {
        unsigned long long h = k0;
        #pragma unroll
        for (int off = 32; off > 0; off >>= 1) {
            unsigned long long o = __shfl_xor(h, off, 64);
            if (o < h) h = o;
        }
        if (lane == r) mywin = h;
        if (k0 == h) {
            k0 = k1; k1 = k2; k2 = k3; k3 = k4; k4 = k5; k5 = k6; k6 = k7; k7 = SENT;
        }
    }
    if (lane < KNN) {
        int j = (int)(unsigned int)(mywin & 0xFFFFFFFFull);
        idx[(b * MNODE + i) * KNN + lane] = j;
        atomicAdd(&cnt[b * MNODE + j], 1);
    }
}

__global__ void dinv_kernel(const int* __restrict__ cnt, float* __restrict__ dinv) {
    int gid = blockIdx.x * blockDim.x + threadIdx.x;
    if (gid >= BM) return;
    float deg = (float)(KNN + cnt[gid]);
    dinv[gid] = 1.0f / sqrtf(deg + 1e-8f);
}

// exclusive prefix sum over cnt[BM] -> offs[BM]; single block of 256 threads
__global__ void __launch_bounds__(256) scan_kernel(const int* __restrict__ cnt,
                                                   int* __restrict__ offs) {
    __shared__ int part[256];
    int tid = threadIdx.x;
    const int per = BM / 256;   // 144
    int base = tid * per;
    int s = 0;
    for (int k = 0; k < per; ++k) s += cnt[base + k];
    part[tid] = s;
    __syncthreads();
    if (tid == 0) {
        int run = 0;
        for (int t = 0; t < 256; ++t) { int tmp = part[t]; part[t] = run; run += tmp; }
    }
    __syncthreads();
    int run = part[tid];
    for (int k = 0; k < per; ++k) { offs[base + k] = run; run += cnt[base + k]; }
}

// scatter each directed edge i->j into j's reverse list (int atomics for slots)
__global__ void fill_kernel(const int* __restrict__ idx, const int* __restrict__ offs,
                            int* __restrict__ fptr, int* __restrict__ rev) {
    int gid = blockIdx.x * blockDim.x + threadIdx.x;
    if (gid >= BM * KNN) return;
    int b = gid / (MNODE * KNN);
    int rem = gid - b * (MNODE * KNN);
    int i = rem / KNN;
    int gj = b * MNODE + idx[gid];
    int pos = atomicAdd(&fptr[gj], 1);
    rev[offs[gj] + pos] = b * MNODE + i;
}

// zA[i][c] = sum over neighbors j (both directions) with j%9==c of w_ij * S[j]
__global__ void __launch_bounds__(256) gather1_kernel(
    const int* __restrict__ idx, const int* __restrict__ offs, const int* __restrict__ cnt,
    const int* __restrict__ rev, const float* __restrict__ dinv, const float* __restrict__ S,
    float* __restrict__ zA) {
    int gi = blockIdx.x * blockDim.x + threadIdx.x;
    if (gi >= BM) return;
    int b = gi / MNODE;
    float acc[2 * CFREQ];
    #pragma unroll
    for (int k = 0; k < 2 * CFREQ; ++k) acc[k] = 0.0f;
    float di = dinv[gi] * 0.5f;   // fold ew/S_SCALE
    #pragma unroll
    for (int k = 0; k < KNN; ++k) {
        int gj = b * MNODE + idx[gi * KNN + k];
        float w = di * dinv[gj];
        int c = gj % CFREQ;
        acc[2 * c + 0] += w * S[gj * 2 + 0];
        acc[2 * c + 1] += w * S[gj * 2 + 1];
    }
    int o = offs[gi], e = o + cnt[gi];
    for (int p = o; p < e; ++p) {
        int gk = rev[p];
        float w = di * dinv[gk];
        int c = gk % CFREQ;
        acc[2 * c + 0] += w * S[gk * 2 + 0];
        acc[2 * c + 1] += w * S[gk * 2 + 1];
    }
    #pragma unroll
    for (int k = 0; k < 2 * CFREQ; ++k) zA[gi * 2 * CFREQ + k] = acc[k];
}

// zB[i][c] = sum over neighbors j (both directions) of w_ij * zA[j][c]
__global__ void __launch_bounds__(256) gather2_kernel(
    const int* __restrict__ idx, const int* __restrict__ offs, const int* __restrict__ cnt,
    const int* __restrict__ rev, const float* __restrict__ dinv, const float* __restrict__ zA,
    float* __restrict__ zB) {
    int gi = blockIdx.x * blockDim.x + threadIdx.x;
    if (gi >= BM) return;
    int b = gi / MNODE;
    float acc[2 * CFREQ];
    #pragma unroll
    for (int k = 0; k < 2 * CFREQ; ++k) acc[k] = 0.0f;
    float di = dinv[gi] * 0.5f;
    #pragma unroll
    for (int k = 0; k < KNN; ++k) {
        int gj = b * MNODE + idx[gi * KNN + k];
        float w = di * dinv[gj];
        const float* za = zA + gj * 2 * CFREQ;
        #pragma unroll
        for (int c = 0; c < CFREQ; ++c) {
            float2 v = ((const float2*)za)[c];
            acc[2 * c + 0] += w * v.x;
            acc[2 * c + 1] += w * v.y;
        }
    }
    int o = offs[gi], e = o + cnt[gi];
    for (int p = o; p < e; ++p) {
        int gk = rev[p];
        float w = di * dinv[gk];
        const float* za = zA + gk * 2 * CFREQ;
        #pragma unroll
        for (int c = 0; c < CFREQ; ++c) {
            float2 v = ((const float2*)za)[c];
            acc[2 * c + 0] += w * v.x;
            acc[2 * c + 1] += w * v.y;
        }
    }
    #pragma unroll
    for (int k = 0; k < 2 * CFREQ; ++k) zB[gi * 2 * CFREQ + k] = acc[k];
}

// FE[c,e] = freq_emb[c,:] @ (Wr + i Wi)^T  (9 x 128 complex)
__global__ void fe_kernel(const float* __restrict__ femb, const float* __restrict__ Wr,
                          const float* __restrict__ Wi, float* __restrict__ FE) {
    int gid = blockIdx.x * blockDim.x + threadIdx.x;
    if (gid >= CFREQ * EMBED) return;
    int c = gid / EMBED;
    int e = gid - c * EMBED;
    float ar = 0.0f, ai = 0.0f;
    for (int k = 0; k < EMBED; ++k) {
        float f = femb[c * EMBED + k];
        ar += f * Wr[e * EMBED + k];
        ai += f * Wi[e * EMBED + k];
    }
    FE[gid * 2 + 0] = ar;
    FE[gid * 2 + 1] = ai;
}

// per row r: z_acc (9 complex) -> u = z_acc . FE -> csilu -> eo projection (complex scalar)
__global__ void __launch_bounds__(256) rowproj_kernel(
    const float* __restrict__ S, const float* __restrict__ zA, const float* __restrict__ zB,
    const float* __restrict__ FE, const float* __restrict__ eoWr, const float* __restrict__ eoWi,
    const float* __restrict__ theta, const float* __restrict__ approx,
    float* __restrict__ Sout) {
    int wave = threadIdx.x >> 6;
    int lane = threadIdx.x & 63;
    int r = blockIdx.x * 4 + wave;
    if (r >= BM) return;
    float a0 = theta[0] * approx[0] + theta[1] * approx[3];
    float a1 = theta[0] * approx[1] + theta[1] * approx[4];
    float a2 = theta[0] * approx[2] + theta[1] * approx[5];
    float ca = a0 - a2, cb = -a1, cc = 2.0f * a2;
    int cr = r % CFREQ;
    float sr = S[r * 2 + 0], si = S[r * 2 + 1];
    int e1 = lane + 64;
    float ur0 = 0.0f, ui0 = 0.0f, ur1 = 0.0f, ui1 = 0.0f;
    #pragma unroll
    for (int c = 0; c < CFREQ; ++c) {
        float zr = cb * zA[(r * CFREQ + c) * 2 + 0] + cc * zB[(r * CFREQ + c) * 2 + 0];
        float zi = cb * zA[(r * CFREQ + c) * 2 + 1] + cc * zB[(r * CFREQ + c) * 2 + 1];
        if (c == cr) { zr += ca * sr; zi += ca * si; }
        float fr0 = FE[(c * EMBED + lane) * 2 + 0], fi0 = FE[(c * EMBED + lane) * 2 + 1];
        float fr1 = FE[(c * EMBED + e1) * 2 + 0],  fi1 = FE[(c * EMBED + e1) * 2 + 1];
        ur0 += zr * fr0 - zi * fi0;  ui0 += zr * fi0 + zi * fr0;
        ur1 += zr * fr1 - zi * fi1;  ui1 += zr * fi1 + zi * fr1;
    }
    float hr0 = silu_f(ur0), hi0 = silu_f(ui0);
    float hr1 = silu_f(ur1), hi1 = silu_f(ui1);
    float wr0 = eoWr[lane], wi0 = eoWi[lane], wr1 = eoWr[e1], wi1 = eoWi[e1];
    float p = hr0 * wr0 - hi0 * wi0 + hr1 * wr1 - hi1 * wi1;
    float q = hr0 * wi0 + hi0 * wr0 + hr1 * wi1 + hi1 * wr1;
    #pragma unroll
    for (int off = 32; off > 0; off >>= 1) {
        p += __shfl_down(p, off, 64);
        q += __shfl_down(q, off, 64);
    }
    if (lane == 0) {
        Sout[r * 2 + 0] = p;
        Sout[r * 2 + 1] = q;
    }
}

// per (b,n): irfft96 -> inorm+silu -> W1 -> inorm+silu -> W2 -> + trend_emb -> W3 -> out
__global__ void __launch_bounds__(128) head_kernel(
    const float* __restrict__ Sout, const float* __restrict__ trend,
    const float* __restrict__ n1w, const float* __restrict__ n1b,
    const float* __restrict__ n2w, const float* __restrict__ n2b,
    const float* __restrict__ W1w, const float* __restrict__ W1b,
    const float* __restrict__ W2w, const float* __restrict__ W2b,
    const float* __restrict__ Wtw, const float* __restrict__ Wtb,
    const float* __restrict__ W3w, const float* __restrict__ W3b,
    float* __restrict__ out) {
    __shared__ float tabc[96], tabs[96], hraw[96], sH[96], tbuf[96];
    __shared__ float srow[18], h2[64], s3[64], red[2];
    __shared__ float wbuf[6240];
    int bn = blockIdx.x;
    int b = bn >> 8;
    int n = bn & 255;
    int tid = threadIdx.x;
    if (tid < 96) {
        double a = 6.283185307179586476925286766559 * (double)tid / 96.0;
        tabc[tid] = (float)cos(a);
        tabs[tid] = (float)sin(a);
        tbuf[tid] = trend[b * TN + tid * NNODE + n];
    }
    if (tid < 18) srow[tid] = Sout[bn * 18 + tid];
    __syncthreads();
    float hv = 0.0f;
    if (tid < 96) {
        float acc = srow[0];   // Im(bin0) ignored by irfft
        #pragma unroll
        for (int c = 1; c < CFREQ; ++c) {
            int k = (c * tid) % 96;
            acc += 2.0f * (srow[2 * c] * tabc[k] - srow[2 * c + 1] * tabs[k]);
        }
        hv = acc * 0.10206207261596575f;  // 1/sqrt(96)
        hraw[tid] = hv;
    }
    __syncthreads();
    if (tid < 64) {
        float v = hraw[tid] + ((tid < 32) ? hraw[64 + tid] : 0.0f);
        #pragma unroll
        for (int off = 32; off > 0; off >>= 1) v += __shfl_down(v, off, 64);
        if (tid == 0) red[0] = v * (1.0f / 96.0f);
    }
    __syncthreads();
    float mu = red[0];
    if (tid < 64) {
        float d0 = hraw[tid] - mu;
        float v = d0 * d0;
        if (tid < 32) { float d1 = hraw[64 + tid] - mu; v += d1 * d1; }
        #pragma unroll
        for (int off = 32; off > 0; off >>= 1) v += __shfl_down(v, off, 64);
        if (tid == 0) red[1] = v * (1.0f / 96.0f);
    }
    __syncthreads();
    float var = red[1];
    if (tid < 96) {
        float xn = (hv - mu) / sqrtf(var + 1e-5f) * n1w[n] + n1b[n];
        sH[tid] = silu_f(xn);
    }
    for (int i = tid; i < HIDDEN * 96; i += 128) {
        int rr = i / 96;
        wbuf[rr * 97 + (i - rr * 96)] = W1w[i];
    }
    __syncthreads();
    float v1 = 0.0f;
    if (tid < 64) {
        float acc = W1b[tid];
        #pragma unroll 8
        for (int t = 0; t < 96; ++t) acc += sH[t] * wbuf[tid * 97 + t];
        v1 = acc;
    }
    if (tid < 64) {
        float s = v1;
        #pragma unroll
        for (int off = 32; off > 0; off >>= 1) s += __shfl_down(s, off, 64);
        s = __shfl(s, 0, 64);
        float mu2 = s * (1.0f / 64.0f);
        float d = v1 - mu2;
        float vs = d * d;
        #pragma unroll
        for (int off = 32; off > 0; off >>= 1) vs += __shfl_down(vs, off, 64);
        vs = __shfl(vs, 0, 64);
        float var2 = vs * (1.0f / 64.0f);
        float xn = (v1 - mu2) / sqrtf(var2 + 1e-5f) * n2w[n] + n2b[n];
        h2[tid] = silu_f(xn);
    }
    __syncthreads();   // wbuf(W1) reads + h2 writes done
    for (int i = tid; i < HIDDEN * HIDDEN; i += 128) {
        wbuf[(i >> 6) * 65 + (i & 63)] = W2w[i];
    }
    __syncthreads();
    float v3 = 0.0f;
    if (tid < 64) {
        float acc = W2b[tid];
        #pragma unroll 8
        for (int h = 0; h < 64; ++h) acc += h2[h] * wbuf[tid * 65 + h];
        v3 = acc;
    }
    __syncthreads();   // wbuf(W2) reads done
    for (int i = tid; i < HIDDEN * 96; i += 128) {
        int rr = i / 96;
        wbuf[rr * 97 + (i - rr * 96)] = Wtw[i];
    }
    __syncthreads();
    if (tid < 64) {
        float acc = Wtb[tid];
        #pragma unroll 8
        for (int t = 0; t < 96; ++t) acc += tbuf[t] * wbuf[tid * 97 + t];
        s3[tid] = v3 + acc;
    }
    __syncthreads();   // wbuf(Wt) reads + s3 writes done
    for (int i = tid; i < 96 * HIDDEN; i += 128) {
        wbuf[(i >> 6) * 65 + (i & 63)] = W3w[i];
    }
    __syncthreads();
    if (tid < 96) {
        float acc = W3b[tid];
        #pragma unroll 8
        for (int h = 0; h < 64; ++h) acc += s3[h] * wbuf[tid * 65 + h];
        out[bn * 96 + tid] = acc;
    }
}

extern "C" void kernel_launch(void* const* d_in, const int* in_sizes, int n_in,
                              void* d_out, int out_size, void* d_ws, size_t ws_size,
                              hipStream_t stream) {
    const float* x     = (const float*)d_in[0];
    const float* approx= (const float*)d_in[1];
    const float* theta = (const float*)d_in[2];
    const float* frWr  = (const float*)d_in[3];
    const float* frWi  = (const float*)d_in[4];
    const float* eoWr  = (const float*)d_in[5];
    const float* eoWi  = (const float*)d_in[6];
    const float* femb  = (const float*)d_in[7];
    const float* n1w   = (const float*)d_in[8];
    const float* n1b   = (const float*)d_in[9];
    const float* n2w   = (const float*)d_in[10];
    const float* n2b   = (const float*)d_in[11];
    const float* W1w   = (const float*)d_in[12];
    const float* W1b   = (const float*)d_in[13];
    const float* W2w   = (const float*)d_in[14];
    const float* W2b   = (const float*)d_in[15];
    const float* Wtw   = (const float*)d_in[16];
    const float* Wtb   = (const float*)d_in[17];
    const float* W3w   = (const float*)d_in[18];
    const float* W3b   = (const float*)d_in[19];
    float* out = (float*)d_out;

    char* ws = (char*)d_ws;
    size_t off = 0;
    auto alloc = [&](size_t bytes) -> void* {
        void* p = ws + off;
        off = (off + bytes + 255) & ~(size_t)255;
        return p;
    };
    float* trend = (float*)alloc((size_t)BATCH * TN * 4);
    float* S     = (float*)alloc((size_t)BM * 2 * 4);
    int*   idx   = (int*)  alloc((size_t)BM * KNN * 4);
    float* dinv  = (float*)alloc((size_t)BM * 4);
    float* FE    = (float*)alloc((size_t)CFREQ * EMBED * 2 * 4);
    float* Sout  = (float*)alloc((size_t)BM * 2 * 4);
    int*   offs  = (int*)  alloc((size_t)BM * 4);
    int*   rev   = (int*)  alloc((size_t)BM * KNN * 4);
    float* zA    = (float*)alloc((size_t)BM * CFREQ * 2 * 4);
    float* zB    = (float*)alloc((size_t)BM * CFREQ * 2 * 4);
    char*  zbase = ws + off;
    int*   cnt   = (int*)  alloc((size_t)BM * 4);
    int*   fptr  = (int*)  alloc((size_t)BM * 4);
    size_t zbytes = (size_t)(ws + off - zbase);

    hipMemsetAsync(zbase, 0, zbytes, stream);   // cnt + fptr only (288 KB)

    trend_kernel<<<(BATCH * TN + 255) / 256, 256, 0, stream>>>(x, trend);
    fft_kernel<<<(BM + 255) / 256, 256, 0, stream>>>(x, trend, S);
    knn_kernel<<<dim3(MNODE / 4, BATCH), 256, 0, stream>>>(S, idx, cnt);
    dinv_kernel<<<(BM + 255) / 256, 256, 0, stream>>>(cnt, dinv);
    scan_kernel<<<1, 256, 0, stream>>>(cnt, offs);
    fill_kernel<<<(BM * KNN + 255) / 256, 256, 0, stream>>>(idx, offs, fptr, rev);
    gather1_kernel<<<(BM + 255) / 256, 256, 0, stream>>>(idx, offs, cnt, rev, dinv, S, zA);
    gather2_kernel<<<(BM + 255) / 256, 256, 0, stream>>>(idx, offs, cnt, rev, dinv, zA, zB);
    fe_kernel<<<(CFREQ * EMBED + 255) / 256, 256, 0, stream>>>(femb, frWr, frWi, FE);
    rowproj_kernel<<<BM / 4, 256, 0, stream>>>(S, zA, zB, FE, eoWr, eoWi, theta, approx, Sout);
    head_kernel<<<BATCH * NNODE, 128, 0, stream>>>(Sout, trend, n1w, n1b, n2w, n2b,
                                                   W1w, W1b, W2w, W2b, Wtw, Wtb, W3w, W3b, out);
}

// Round 18
// 371.070 us; speedup vs baseline: 1.1486x; 1.0141x over previous
//
#include <hip/hip_runtime.h>
#include <math.h>
#include <float.h>

#define BATCH 16
#define SEQ 96
#define NNODE 256
#define CFREQ 9
#define MNODE (NNODE * CFREQ)      // 2304
#define BM (BATCH * MNODE)         // 36864
#define KNN 8
#define EMBED 128
#define HIDDEN 64
#define TN (SEQ * NNODE)           // 24576
#define KCAP 256

__constant__ float COS16[16] = {
    1.0f, 0.9238795325112867f, 0.7071067811865476f, 0.3826834323650898f,
    0.0f, -0.3826834323650898f, -0.7071067811865476f, -0.9238795325112867f,
    -1.0f, -0.9238795325112867f, -0.7071067811865476f, -0.3826834323650898f,
    0.0f, 0.3826834323650898f, 0.7071067811865476f, 0.9238795325112867f};
__constant__ float SIN16[16] = {
    0.0f, 0.3826834323650898f, 0.7071067811865476f, 0.9238795325112867f,
    1.0f, 0.9238795325112867f, 0.7071067811865476f, 0.3826834323650898f,
    0.0f, -0.3826834323650898f, -0.7071067811865476f, -0.9238795325112867f,
    -1.0f, -0.9238795325112867f, -0.7071067811865476f, -0.3826834323650898f};

static __device__ __forceinline__ float silu_f(float x) {
    return x / (1.0f + expf(-x));
}

// trend[b,t,n] = (x[t-1]+x[t]+x[t+1])/3 with edge clamp; layout (B,T,N)
__global__ void trend_kernel(const float* __restrict__ x, float* __restrict__ trend) {
    int gid = blockIdx.x * blockDim.x + threadIdx.x;
    if (gid >= BATCH * TN) return;
    int b = gid / TN;
    int rem = gid - b * TN;
    int t = rem / NNODE;
    int n = rem - t * NNODE;
    int tm = t > 0 ? t - 1 : 0;
    int tp = t < SEQ - 1 ? t + 1 : SEQ - 1;
    const float* xb = x + b * TN;
    float v = (xb[tm * NNODE + n] + xb[t * NNODE + n] + xb[tp * NNODE + n]) * (1.0f / 3.0f);
    trend[gid] = v;
}

// S[b, m] = ortho-rfft16 of (x - trend) over first 16 t; m = n*9 + c
__global__ void fft_kernel(const float* __restrict__ x, const float* __restrict__ trend,
                           float* __restrict__ S) {
    int gid = blockIdx.x * blockDim.x + threadIdx.x;
    if (gid >= BM) return;
    int b = gid / MNODE;
    int m = gid - b * MNODE;
    int n = m / CFREQ;
    int c = m - n * CFREQ;
    const float* xb = x + b * TN + n;
    const float* tb = trend + b * TN + n;
    float re = 0.0f, im = 0.0f;
    #pragma unroll
    for (int t = 0; t < 16; ++t) {
        float s = xb[t * NNODE] - tb[t * NNODE];
        int k = (c * t) & 15;
        re += s * COS16[k];
        im -= s * SIN16[k];
    }
    S[gid * 2 + 0] = re * 0.25f;
    S[gid * 2 + 1] = im * 0.25f;
}

// One WAVE per row, 4 rows per 256-block. Exact top-8 via 3-phase filter
// (round-17's PASSING structure; only change: 6-shuffle threshold instead of
// the 48-shuffle 8-round elimination):
//  P1: 36 lane-candidate distances cached in regs; per-lane min.
//  T : max over 8 disjoint 8-lane groups of group-min of lane minima.
//      Each group-min is a real candidate distance from a disjoint lane set,
//      so >=8 candidates have d <= T  =>  T >= true d8 (superset filter).
//  P2: append u64 keys (sortable_d | j) of candidates with d <= T to row LDS buf.
//  P3: exact u64 top-8 + 8-round merge over the small buffer.
//  Overflow (> KCAP, pathological ties only) -> exact scan over cached d.
__global__ void __launch_bounds__(256, 8) knn_kernel(const float* __restrict__ S,
                                                     int* __restrict__ idx, int* __restrict__ cnt) {
    __shared__ float2 f[MNODE];                        // 18432 B
    __shared__ unsigned long long kbuf[4][KCAP];       // 8192 B
    __shared__ int bcnt[4];
    int b = blockIdx.y;
    int tid = threadIdx.x;
    for (int t = tid; t < MNODE; t += 256) {
        f[t] = make_float2(S[(b * MNODE + t) * 2 + 0], S[(b * MNODE + t) * 2 + 1]);
    }
    if (tid < 4) bcnt[tid] = 0;
    __syncthreads();
    int wave = tid >> 6, lane = tid & 63;
    int i = blockIdx.x * 4 + wave;
    float2 fi = f[i];
    float xi0 = fi.x, yi0 = fi.y;
    float sqi = __fadd_rn(__fmul_rn(xi0, xi0), __fmul_rn(yi0, yi0));

    // Phase 1: distances cached, per-lane min
    float d[36];
    float mymin = FLT_MAX;
    #pragma unroll
    for (int k = 0; k < 36; ++k) {
        int j = lane + (k << 6);
        float2 fj = f[j];
        float sqj = __fadd_rn(__fmul_rn(fj.x, fj.x), __fmul_rn(fj.y, fj.y));
        float dot = __fadd_rn(__fmul_rn(xi0, fj.x), __fmul_rn(yi0, fj.y));
        float dd = __fsub_rn(__fadd_rn(sqi, sqj), __fmul_rn(2.0f, dot));
        if (j == i) dd = FLT_MAX;
        d[k] = dd;
        mymin = fminf(mymin, dd);
    }
    // Threshold: 6 dependent shuffles. Group-min (lanes differing in bits 0-2),
    // then max across the 8 groups (bits 3-5).
    float g = mymin;
    g = fminf(g, __shfl_xor(g, 1, 64));
    g = fminf(g, __shfl_xor(g, 2, 64));
    g = fminf(g, __shfl_xor(g, 4, 64));
    float T = g;
    T = fmaxf(T, __shfl_xor(T, 8, 64));
    T = fmaxf(T, __shfl_xor(T, 16, 64));
    T = fmaxf(T, __shfl_xor(T, 32, 64));
    // Phase 2: append survivors' exact keys
    unsigned long long* mybuf = kbuf[wave];
    #pragma unroll
    for (int k = 0; k < 36; ++k) {
        if (d[k] <= T) {
            int j = lane + (k << 6);
            unsigned int bits = __float_as_uint(d[k]);
            if (bits == 0x80000000u) bits = 0u;
            unsigned int s = bits ^ (unsigned int)(((int)bits >> 31) | 0x80000000);
            unsigned long long key = ((unsigned long long)s << 32) | (unsigned int)j;
            int p = atomicAdd(&bcnt[wave], 1);
            if (p < KCAP) mybuf[p] = key;
        }
    }
    __syncthreads();   // make appends visible (block-uniform point)

    const unsigned long long SENT = ~0ull;
    unsigned long long k0 = SENT, k1 = SENT, k2 = SENT, k3 = SENT,
                       k4 = SENT, k5 = SENT, k6 = SENT, k7 = SENT;
    auto insert = [&](unsigned long long key) {
        if (key < k7) {
            k7 = key;
            if (k7 < k6) { unsigned long long t = k6; k6 = k7; k7 = t; }
            if (k6 < k5) { unsigned long long t = k5; k5 = k6; k6 = t; }
            if (k5 < k4) { unsigned long long t = k4; k4 = k5; k5 = t; }
            if (k4 < k3) { unsigned long long t = k3; k3 = k4; k4 = t; }
            if (k3 < k2) { unsigned long long t = k2; k2 = k3; k3 = t; }
            if (k2 < k1) { unsigned long long t = k1; k1 = k2; k2 = t; }
            if (k1 < k0) { unsigned long long t = k0; k0 = k1; k1 = t; }
        }
    };
    int total = bcnt[wave];
    if (total > KCAP) {
        // pathological ties: exact scan over cached distances
        #pragma unroll
        for (int k = 0; k < 36; ++k) {
            int j = lane + (k << 6);
            unsigned int bits = __float_as_uint(d[k]);
            if (bits == 0x80000000u) bits = 0u;
            unsigned int s = bits ^ (unsigned int)(((int)bits >> 31) | 0x80000000);
            insert(((unsigned long long)s << 32) | (unsigned int)j);
        }
    } else {
        for (int p = lane; p < total; p += 64) insert(mybuf[p]);
    }
    // 8-round wave merge: lane r keeps winner r
    unsigned long long mywin = 0;
    #pragma unroll
    for (int r = 0; r < KNN; ++r) {
        unsigned long long h = k0;
        #pragma unroll
        for (int off = 32; off > 0; off >>= 1) {
            unsigned long long o = __shfl_xor(h, off, 64);
            if (o < h) h = o;
        }
        if (lane == r) mywin = h;
        if (k0 == h) {
            k0 = k1; k1 = k2; k2 = k3; k3 = k4; k4 = k5; k5 = k6; k6 = k7; k7 = SENT;
        }
    }
    if (lane < KNN) {
        int j = (int)(unsigned int)(mywin & 0xFFFFFFFFull);
        idx[(b * MNODE + i) * KNN + lane] = j;
        atomicAdd(&cnt[b * MNODE + j], 1);
    }
}

__global__ void dinv_kernel(const int* __restrict__ cnt, float* __restrict__ dinv) {
    int gid = blockIdx.x * blockDim.x + threadIdx.x;
    if (gid >= BM) return;
    float deg = (float)(KNN + cnt[gid]);
    dinv[gid] = 1.0f / sqrtf(deg + 1e-8f);
}

// exclusive prefix sum over cnt[BM] -> offs[BM]; single block of 256 threads
__global__ void __launch_bounds__(256) scan_kernel(const int* __restrict__ cnt,
                                                   int* __restrict__ offs) {
    __shared__ int part[256];
    int tid = threadIdx.x;
    const int per = BM / 256;   // 144
    int base = tid * per;
    int s = 0;
    for (int k = 0; k < per; ++k) s += cnt[base + k];
    part[tid] = s;
    __syncthreads();
    if (tid == 0) {
        int run = 0;
        for (int t = 0; t < 256; ++t) { int tmp = part[t]; part[t] = run; run += tmp; }
    }
    __syncthreads();
    int run = part[tid];
    for (int k = 0; k < per; ++k) { offs[base + k] = run; run += cnt[base + k]; }
}

// scatter each directed edge i->j into j's reverse list (int atomics for slots)
__global__ void fill_kernel(const int* __restrict__ idx, const int* __restrict__ offs,
                            int* __restrict__ fptr, int* __restrict__ rev) {
    int gid = blockIdx.x * blockDim.x + threadIdx.x;
    if (gid >= BM * KNN) return;
    int b = gid / (MNODE * KNN);
    int rem = gid - b * (MNODE * KNN);
    int i = rem / KNN;
    int gj = b * MNODE + idx[gid];
    int pos = atomicAdd(&fptr[gj], 1);
    rev[offs[gj] + pos] = b * MNODE + i;
}

// zA[i][c] = sum over neighbors j (both directions) with j%9==c of w_ij * S[j]
__global__ void __launch_bounds__(256) gather1_kernel(
    const int* __restrict__ idx, const int* __restrict__ offs, const int* __restrict__ cnt,
    const int* __restrict__ rev, const float* __restrict__ dinv, const float* __restrict__ S,
    float* __restrict__ zA) {
    int gi = blockIdx.x * blockDim.x + threadIdx.x;
    if (gi >= BM) return;
    int b = gi / MNODE;
    float acc[2 * CFREQ];
    #pragma unroll
    for (int k = 0; k < 2 * CFREQ; ++k) acc[k] = 0.0f;
    float di = dinv[gi] * 0.5f;   // fold ew/S_SCALE
    #pragma unroll
    for (int k = 0; k < KNN; ++k) {
        int gj = b * MNODE + idx[gi * KNN + k];
        float w = di * dinv[gj];
        int c = gj % CFREQ;
        acc[2 * c + 0] += w * S[gj * 2 + 0];
        acc[2 * c + 1] += w * S[gj * 2 + 1];
    }
    int o = offs[gi], e = o + cnt[gi];
    for (int p = o; p < e; ++p) {
        int gk = rev[p];
        float w = di * dinv[gk];
        int c = gk % CFREQ;
        acc[2 * c + 0] += w * S[gk * 2 + 0];
        acc[2 * c + 1] += w * S[gk * 2 + 1];
    }
    #pragma unroll
    for (int k = 0; k < 2 * CFREQ; ++k) zA[gi * 2 * CFREQ + k] = acc[k];
}

// zB[i][c] = sum over neighbors j (both directions) of w_ij * zA[j][c]
__global__ void __launch_bounds__(256) gather2_kernel(
    const int* __restrict__ idx, const int* __restrict__ offs, const int* __restrict__ cnt,
    const int* __restrict__ rev, const float* __restrict__ dinv, const float* __restrict__ zA,
    float* __restrict__ zB) {
    int gi = blockIdx.x * blockDim.x + threadIdx.x;
    if (gi >= BM) return;
    int b = gi / MNODE;
    float acc[2 * CFREQ];
    #pragma unroll
    for (int k = 0; k < 2 * CFREQ; ++k) acc[k] = 0.0f;
    float di = dinv[gi] * 0.5f;
    #pragma unroll
    for (int k = 0; k < KNN; ++k) {
        int gj = b * MNODE + idx[gi * KNN + k];
        float w = di * dinv[gj];
        const float* za = zA + gj * 2 * CFREQ;
        #pragma unroll
        for (int c = 0; c < CFREQ; ++c) {
            float2 v = ((const float2*)za)[c];
            acc[2 * c + 0] += w * v.x;
            acc[2 * c + 1] += w * v.y;
        }
    }
    int o = offs[gi], e = o + cnt[gi];
    for (int p = o; p < e; ++p) {
        int gk = rev[p];
        float w = di * dinv[gk];
        const float* za = zA + gk * 2 * CFREQ;
        #pragma unroll
        for (int c = 0; c < CFREQ; ++c) {
            float2 v = ((const float2*)za)[c];
            acc[2 * c + 0] += w * v.x;
            acc[2 * c + 1] += w * v.y;
        }
    }
    #pragma unroll
    for (int k = 0; k < 2 * CFREQ; ++k) zB[gi * 2 * CFREQ + k] = acc[k];
}

// FE[c,e] = freq_emb[c,:] @ (Wr + i Wi)^T  (9 x 128 complex)
__global__ void fe_kernel(const float* __restrict__ femb, const float* __restrict__ Wr,
                          const float* __restrict__ Wi, float* __restrict__ FE) {
    int gid = blockIdx.x * blockDim.x + threadIdx.x;
    if (gid >= CFREQ * EMBED) return;
    int c = gid / EMBED;
    int e = gid - c * EMBED;
    float ar = 0.0f, ai = 0.0f;
    for (int k = 0; k < EMBED; ++k) {
        float f = femb[c * EMBED + k];
        ar += f * Wr[e * EMBED + k];
        ai += f * Wi[e * EMBED + k];
    }
    FE[gid * 2 + 0] = ar;
    FE[gid * 2 + 1] = ai;
}

// per row r: z_acc (9 complex) -> u = z_acc . FE -> csilu -> eo projection (complex scalar)
__global__ void __launch_bounds__(256) rowproj_kernel(
    const float* __restrict__ S, const float* __restrict__ zA, const float* __restrict__ zB,
    const float* __restrict__ FE, const float* __restrict__ eoWr, const float* __restrict__ eoWi,
    const float* __restrict__ theta, const float* __restrict__ approx,
    float* __restrict__ Sout) {
    int wave = threadIdx.x >> 6;
    int lane = threadIdx.x & 63;
    int r = blockIdx.x * 4 + wave;
    if (r >= BM) return;
    float a0 = theta[0] * approx[0] + theta[1] * approx[3];
    float a1 = theta[0] * approx[1] + theta[1] * approx[4];
    float a2 = theta[0] * approx[2] + theta[1] * approx[5];
    float ca = a0 - a2, cb = -a1, cc = 2.0f * a2;
    int cr = r % CFREQ;
    float sr = S[r * 2 + 0], si = S[r * 2 + 1];
    int e1 = lane + 64;
    float ur0 = 0.0f, ui0 = 0.0f, ur1 = 0.0f, ui1 = 0.0f;
    #pragma unroll
    for (int c = 0; c < CFREQ; ++c) {
        float zr = cb * zA[(r * CFREQ + c) * 2 + 0] + cc * zB[(r * CFREQ + c) * 2 + 0];
        float zi = cb * zA[(r * CFREQ + c) * 2 + 1] + cc * zB[(r * CFREQ + c) * 2 + 1];
        if (c == cr) { zr += ca * sr; zi += ca * si; }
        float fr0 = FE[(c * EMBED + lane) * 2 + 0], fi0 = FE[(c * EMBED + lane) * 2 + 1];
        float fr1 = FE[(c * EMBED + e1) * 2 + 0],  fi1 = FE[(c * EMBED + e1) * 2 + 1];
        ur0 += zr * fr0 - zi * fi0;  ui0 += zr * fi0 + zi * fr0;
        ur1 += zr * fr1 - zi * fi1;  ui1 += zr * fi1 + zi * fr1;
    }
    float hr0 = silu_f(ur0), hi0 = silu_f(ui0);
    float hr1 = silu_f(ur1), hi1 = silu_f(ui1);
    float wr0 = eoWr[lane], wi0 = eoWi[lane], wr1 = eoWr[e1], wi1 = eoWi[e1];
    float p = hr0 * wr0 - hi0 * wi0 + hr1 * wr1 - hi1 * wi1;
    float q = hr0 * wi0 + hi0 * wr0 + hr1 * wi1 + hi1 * wr1;
    #pragma unroll
    for (int off = 32; off > 0; off >>= 1) {
        p += __shfl_down(p, off, 64);
        q += __shfl_down(q, off, 64);
    }
    if (lane == 0) {
        Sout[r * 2 + 0] = p;
        Sout[r * 2 + 1] = q;
    }
}

// per (b,n): irfft96 -> inorm+silu -> W1 -> inorm+silu -> W2 -> + trend_emb -> W3 -> out
__global__ void __launch_bounds__(128) head_kernel(
    const float* __restrict__ Sout, const float* __restrict__ trend,
    const float* __restrict__ n1w, const float* __restrict__ n1b,
    const float* __restrict__ n2w, const float* __restrict__ n2b,
    const float* __restrict__ W1w, const float* __restrict__ W1b,
    const float* __restrict__ W2w, const float* __restrict__ W2b,
    const float* __restrict__ Wtw, const float* __restrict__ Wtb,
    const float* __restrict__ W3w, const float* __restrict__ W3b,
    float* __restrict__ out) {
    __shared__ float tabc[96], tabs[96], hraw[96], sH[96], tbuf[96];
    __shared__ float srow[18], h2[64], s3[64], red[2];
    __shared__ float wbuf[6240];
    int bn = blockIdx.x;
    int b = bn >> 8;
    int n = bn & 255;
    int tid = threadIdx.x;
    if (tid < 96) {
        double a = 6.283185307179586476925286766559 * (double)tid / 96.0;
        tabc[tid] = (float)cos(a);
        tabs[tid] = (float)sin(a);
        tbuf[tid] = trend[b * TN + tid * NNODE + n];
    }
    if (tid < 18) srow[tid] = Sout[bn * 18 + tid];
    __syncthreads();
    float hv = 0.0f;
    if (tid < 96) {
        float acc = srow[0];   // Im(bin0) ignored by irfft
        #pragma unroll
        for (int c = 1; c < CFREQ; ++c) {
            int k = (c * tid) % 96;
            acc += 2.0f * (srow[2 * c] * tabc[k] - srow[2 * c + 1] * tabs[k]);
        }
        hv = acc * 0.10206207261596575f;  // 1/sqrt(96)
        hraw[tid] = hv;
    }
    __syncthreads();
    if (tid < 64) {
        float v = hraw[tid] + ((tid < 32) ? hraw[64 + tid] : 0.0f);
        #pragma unroll
        for (int off = 32; off > 0; off >>= 1) v += __shfl_down(v, off, 64);
        if (tid == 0) red[0] = v * (1.0f / 96.0f);
    }
    __syncthreads();
    float mu = red[0];
    if (tid < 64) {
        float d0 = hraw[tid] - mu;
        float v = d0 * d0;
        if (tid < 32) { float d1 = hraw[64 + tid] - mu; v += d1 * d1; }
        #pragma unroll
        for (int off = 32; off > 0; off >>= 1) v += __shfl_down(v, off, 64);
        if (tid == 0) red[1] = v * (1.0f / 96.0f);
    }
    __syncthreads();
    float var = red[1];
    if (tid < 96) {
        float xn = (hv - mu) / sqrtf(var + 1e-5f) * n1w[n] + n1b[n];
        sH[tid] = silu_f(xn);
    }
    for (int i = tid; i < HIDDEN * 96; i += 128) {
        int rr = i / 96;
        wbuf[rr * 97 + (i - rr * 96)] = W1w[i];
    }
    __syncthreads();
    float v1 = 0.0f;
    if (tid < 64) {
        float acc = W1b[tid];
        #pragma unroll 8
        for (int t = 0; t < 96; ++t) acc += sH[t] * wbuf[tid * 97 + t];
        v1 = acc;
    }
    if (tid < 64) {
        float s = v1;
        #pragma unroll
        for (int off = 32; off > 0; off >>= 1) s += __shfl_down(s, off, 64);
        s = __shfl(s, 0, 64);
        float mu2 = s * (1.0f / 64.0f);
        float d = v1 - mu2;
        float vs = d * d;
        #pragma unroll
        for (int off = 32; off > 0; off >>= 1) vs += __shfl_down(vs, off, 64);
        vs = __shfl(vs, 0, 64);
        float var2 = vs * (1.0f / 64.0f);
        float xn = (v1 - mu2) / sqrtf(var2 + 1e-5f) * n2w[n] + n2b[n];
        h2[tid] = silu_f(xn);
    }
    __syncthreads();   // wbuf(W1) reads + h2 writes done
    for (int i = tid; i < HIDDEN * HIDDEN; i += 128) {
        wbuf[(i >> 6) * 65 + (i & 63)] = W2w[i];
    }
    __syncthreads();
    float v3 = 0.0f;
    if (tid < 64) {
        float acc = W2b[tid];
        #pragma unroll 8
        for (int h = 0; h < 64; ++h) acc += h2[h] * wbuf[tid * 65 + h];
        v3 = acc;
    }
    __syncthreads();   // wbuf(W2) reads done
    for (int i = tid; i < HIDDEN * 96; i += 128) {
        int rr = i / 96;
        wbuf[rr * 97 + (i - rr * 96)] = Wtw[i];
    }
    __syncthreads();
    if (tid < 64) {
        float acc = Wtb[tid];
        #pragma unroll 8
        for (int t = 0; t < 96; ++t) acc += tbuf[t] * wbuf[tid * 97 + t];
        s3[tid] = v3 + acc;
    }
    __syncthreads();   // wbuf(Wt) reads + s3 writes done
    for (int i = tid; i < 96 * HIDDEN; i += 128) {
        wbuf[(i >> 6) * 65 + (i & 63)] = W3w[i];
    }
    __syncthreads();
    if (tid < 96) {
        float acc = W3b[tid];
        #pragma unroll 8
        for (int h = 0; h < 64; ++h) acc += s3[h] * wbuf[tid * 65 + h];
        out[bn * 96 + tid] = acc;
    }
}

extern "C" void kernel_launch(void* const* d_in, const int* in_sizes, int n_in,
                              void* d_out, int out_size, void* d_ws, size_t ws_size,
                              hipStream_t stream) {
    const float* x     = (const float*)d_in[0];
    const float* approx= (const float*)d_in[1];
    const float* theta = (const float*)d_in[2];
    const float* frWr  = (const float*)d_in[3];
    const float* frWi  = (const float*)d_in[4];
    const float* eoWr  = (const float*)d_in[5];
    const float* eoWi  = (const float*)d_in[6];
    const float* femb  = (const float*)d_in[7];
    const float* n1w   = (const float*)d_in[8];
    const float* n1b   = (const float*)d_in[9];
    const float* n2w   = (const float*)d_in[10];
    const float* n2b   = (const float*)d_in[11];
    const float* W1w   = (const float*)d_in[12];
    const float* W1b   = (const float*)d_in[13];
    const float* W2w   = (const float*)d_in[14];
    const float* W2b   = (const float*)d_in[15];
    const float* Wtw   = (const float*)d_in[16];
    const float* Wtb   = (const float*)d_in[17];
    const float* W3w   = (const float*)d_in[18];
    const float* W3b   = (const float*)d_in[19];
    float* out = (float*)d_out;

    char* ws = (char*)d_ws;
    size_t off = 0;
    auto alloc = [&](size_t bytes) -> void* {
        void* p = ws + off;
        off = (off + bytes + 255) & ~(size_t)255;
        return p;
    };
    float* trend = (float*)alloc((size_t)BATCH * TN * 4);
    float* S     = (float*)alloc((size_t)BM * 2 * 4);
    int*   idx   = (int*)  alloc((size_t)BM * KNN * 4);
    float* dinv  = (float*)alloc((size_t)BM * 4);
    float* FE    = (float*)alloc((size_t)CFREQ * EMBED * 2 * 4);
    float* Sout  = (float*)alloc((size_t)BM * 2 * 4);
    int*   offs  = (int*)  alloc((size_t)BM * 4);
    int*   rev   = (int*)  alloc((size_t)BM * KNN * 4);
    float* zA    = (float*)alloc((size_t)BM * CFREQ * 2 * 4);
    float* zB    = (float*)alloc((size_t)BM * CFREQ * 2 * 4);
    char*  zbase = ws + off;
    int*   cnt   = (int*)  alloc((size_t)BM * 4);
    int*   fptr  = (int*)  alloc((size_t)BM * 4);
    size_t zbytes = (size_t)(ws + off - zbase);

    hipMemsetAsync(zbase, 0, zbytes, stream);   // cnt + fptr only (288 KB)

    trend_kernel<<<(BATCH * TN + 255) / 256, 256, 0, stream>>>(x, trend);
    fft_kernel<<<(BM + 255) / 256, 256, 0, stream>>>(x, trend, S);
    knn_kernel<<<dim3(MNODE / 4, BATCH), 256, 0, stream>>>(S, idx, cnt);
    dinv_kernel<<<(BM + 255) / 256, 256, 0, stream>>>(cnt, dinv);
    scan_kernel<<<1, 256, 0, stream>>>(cnt, offs);
    fill_kernel<<<(BM * KNN + 255) / 256, 256, 0, stream>>>(idx, offs, fptr, rev);
    gather1_kernel<<<(BM + 255) / 256, 256, 0, stream>>>(idx, offs, cnt, rev, dinv, S, zA);
    gather2_kernel<<<(BM + 255) / 256, 256, 0, stream>>>(idx, offs, cnt, rev, dinv, zA, zB);
    fe_kernel<<<(CFREQ * EMBED + 255) / 256, 256, 0, stream>>>(femb, frWr, frWi, FE);
    rowproj_kernel<<<BM / 4, 256, 0, stream>>>(S, zA, zB, FE, eoWr, eoWi, theta, approx, Sout);
    head_kernel<<<BATCH * NNODE, 128, 0, stream>>>(Sout, trend, n1w, n1b, n2w, n2b,
                                                   W1w, W1b, W2w, W2b, Wtw, Wtb, W3w, W3b, out);
}